// Round 6
// baseline (217.239 us; speedup 1.0000x reference)
//
#include <hip/hip_runtime.h>
#include <stdint.h>

typedef uint32_t u32;
typedef unsigned long long u64;

#define NB 8
#define NPER 4000
#define NC 91
#define NCLS 90
#define NDET 100
#define CHUNKS 32
#define RPB 125        // rows per k_score block = NPER/CHUNKS
#define LBIN 16        // LDS bin capacity per class per block (avg ~5.6 used)
#define BINCAP 512     // global bin capacity per (image,class); avg ~180
#define CSTRIDE 16     // u32 stride: one counter per 64B line (atomic serialization)
#define SURVCAP 9216   // >= 90*100
#define FKCAP 1024     // k_top final pool (100 + score ties)

// ---------------------------------------------------------------- decode ----
// bit-identical to reference op order (verified absmax 0.0 in R1-R5)
__device__ __forceinline__ float4 decode_clip(float4 rel, float w, float h,
                                              float cx, float cy, float W, float H) {
  const float XCLIP = 4.135166556742356f;  // log(1000/16)
  float dx = rel.x / 10.0f;
  float dy = rel.y / 10.0f;
  float dw = fminf(rel.z / 5.0f, XCLIP);
  float dh = fminf(rel.w / 5.0f, XCLIP);
  float qcx = dx * w + cx;
  float qcy = dy * h + cy;
  float qw = expf(dw) * w;
  float qh = expf(dh) * h;
  float x1 = qcx - 0.5f * qw, y1 = qcy - 0.5f * qh;
  float x2 = qcx + 0.5f * qw, y2 = qcy + 0.5f * qh;
  x1 = fminf(fmaxf(x1, 0.0f), W);
  x2 = fminf(fmaxf(x2, 0.0f), W);
  y1 = fminf(fmaxf(y1, 0.0f), H);
  y2 = fminf(fmaxf(y2, 0.0f), H);
  return make_float4(x1, y1, x2, y2);
}

// ---------------------------------------------------------------- kernels ---
__global__ __launch_bounds__(1024) void k_zero(u32* bin_cnt, u32* surv_cnt) {
  int t = threadIdx.x;
  for (int j = t; j < NB * NCLS * CSTRIDE; j += 1024) bin_cnt[j] = 0u;
  if (t < NB) surv_cnt[t] = 0u;
}

// Front-end: softmax + decode + filter in ONE pass. One wave per row; block
// covers 125 consecutive rows (boxreg gathers stay in a 182 KB L2-friendly
// window). Candidates failing MIN_SIZE are dropped here (== reference's
// valid-mask exclusion). Survive -> (key, decoded box) into LDS class bins,
// flushed cooperatively with one global atomic per non-empty class.
__global__ __launch_bounds__(1024) void k_score(const float* __restrict__ logits,
    const float* __restrict__ boxreg, const float* __restrict__ props,
    const int* __restrict__ dh, const int* __restrict__ dw,
    u32* bin_cnt, u64* bins_key, float4* bins_box) {
  __shared__ u64 s_key[NCLS][LBIN];
  __shared__ float4 s_box[NCLS][LBIN];
  __shared__ u32 s_cnt[NCLS];
  __shared__ u32 s_base[NCLS];
  __shared__ u32 s_cl[NCLS];
  int tid = threadIdx.x;
  int b = blockIdx.x / CHUNKS;
  int chunk = blockIdx.x % CHUNKS;
  int wave = tid >> 6, lane = tid & 63;
  if (tid < NCLS) s_cnt[tid] = 0u;
  __syncthreads();

  float H = (float)dh[0], W = (float)dw[0];
  const float4* props4 = (const float4*)props;
  const float4* breg4 = (const float4*)boxreg;

  for (int rloc = wave; rloc < RPB; rloc += 16) {
    int rl = chunk * RPB + rloc;
    int r = b * NPER + rl;
    const float* lrow = logits + (size_t)r * NC;
    float xA = lrow[lane];
    float xB = (lane < NC - 64) ? lrow[64 + lane] : -3.0e38f;
    float mx = fmaxf(xA, xB);
    for (int o = 32; o; o >>= 1) mx = fmaxf(mx, __shfl_xor(mx, o));
    float eA = expf(xA - mx);
    float eB = (lane < NC - 64) ? expf(xB - mx) : 0.0f;
    float sm = eA + eB;
    for (int o = 32; o; o >>= 1) sm += __shfl_xor(sm, o);
    float sA = eA / sm;
    float sB = eB / sm;
    bool eA_ok = (lane >= 1) && (sA > 0.05f);
    bool eB_ok = (lane < NC - 64) && (sB > 0.05f);
    if (eA_ok || eB_ok) {
      float4 p = props4[r];
      float w = p.z - p.x, h = p.w - p.y;
      float cx = p.x + 0.5f * w, cy = p.y + 0.5f * h;
      if (eA_ok) {
        float4 raw = decode_clip(breg4[(size_t)r * NC + lane], w, h, cx, cy, W, H);
        if (((raw.z - raw.x) >= 0.01f) && ((raw.w - raw.y) >= 0.01f)) {
          int ci = lane - 1;
          u32 orig = (u32)(rl * NCLS + ci);
          u64 key = ((u64)__float_as_uint(sA) << 22) | (u64)(0x3FFFFFu - orig);
          u32 lp = atomicAdd(&s_cnt[ci], 1u);
          if (lp < LBIN) { s_key[ci][lp] = key; s_box[ci][lp] = raw; }
          else {  // rare overflow: direct global (slot disjoint via same counter)
            u32 gp = atomicAdd(&bin_cnt[(b * NCLS + ci) * CSTRIDE], 1u);
            if (gp < BINCAP) {
              size_t o = ((size_t)b * NCLS + ci) * BINCAP + gp;
              bins_key[o] = key; bins_box[o] = raw;
            }
          }
        }
      }
      if (eB_ok) {
        float4 raw = decode_clip(breg4[(size_t)r * NC + 64 + lane], w, h, cx, cy, W, H);
        if (((raw.z - raw.x) >= 0.01f) && ((raw.w - raw.y) >= 0.01f)) {
          int ci = 63 + lane;
          u32 orig = (u32)(rl * NCLS + ci);
          u64 key = ((u64)__float_as_uint(sB) << 22) | (u64)(0x3FFFFFu - orig);
          u32 lp = atomicAdd(&s_cnt[ci], 1u);
          if (lp < LBIN) { s_key[ci][lp] = key; s_box[ci][lp] = raw; }
          else {
            u32 gp = atomicAdd(&bin_cnt[(b * NCLS + ci) * CSTRIDE], 1u);
            if (gp < BINCAP) {
              size_t o = ((size_t)b * NCLS + ci) * BINCAP + gp;
              bins_key[o] = key; bins_box[o] = raw;
            }
          }
        }
      }
    }
  }
  __syncthreads();
  if (tid < NCLS) {
    u32 cl = s_cnt[tid];
    if (cl > LBIN) cl = LBIN;
    s_cl[tid] = cl;
    s_base[tid] = cl ? atomicAdd(&bin_cnt[(b * NCLS + tid) * CSTRIDE], cl) : 0u;
  }
  __syncthreads();
  for (int idx = tid; idx < NCLS * LBIN; idx += 1024) {  // cooperative flush
    int ci = idx / LBIN, j = idx % LBIN;
    if ((u32)j < s_cl[ci]) {
      u32 p = s_base[ci] + (u32)j;
      if (p < BINCAP) {
        size_t o = ((size_t)b * NCLS + ci) * BINCAP + p;
        bins_key[o] = s_key[ci][j];
        bins_box[o] = s_box[ci][j];
      }
    }
  }
}

// Per-(image,class) greedy NMS. 256 threads: coalesced stage of keys+boxes
// into LDS, 4-wave bitonic sort (key,id), then waves 1-3 retire and wave 0
// runs ballot-greedy entirely LDS-resident with NO barriers.
__global__ __launch_bounds__(256) void k_nms_class(const u32* __restrict__ bin_cnt,
    const u64* __restrict__ bins_key, const float4* __restrict__ bins_box,
    u32* surv_cnt, u64* skey, float4* sbox,
    const int* __restrict__ dh, const int* __restrict__ dw) {
  __shared__ u64 k[BINCAP];
  __shared__ u32 id[BINCAP];
  __shared__ float4 box[BINCAP];
  __shared__ float4 s_sb[NDET];   // survivor offset boxes (IoU space)
  __shared__ float s_sa[NDET];
  __shared__ u64 s_sk[NDET];
  __shared__ u32 s_sid[NDET];

  int b = blockIdx.x / NCLS;
  int ci = blockIdx.x % NCLS;
  u32 cnt = bin_cnt[(b * NCLS + ci) * CSTRIDE];
  int n = (int)((cnt < BINCAP) ? cnt : BINCAP);
  if (n <= 0) return;

  int tid = threadIdx.x;
  float H = (float)dh[0], W = (float)dw[0];
  float loff = (fmaxf(H, W) + 1.0f) * (float)(ci + 1);
  size_t binb = ((size_t)b * NCLS + ci) * BINCAP;

  int m = 1;
  while (m < n) m <<= 1;
  if (m < 2) m = 2;
  for (int j = tid; j < m; j += 256) {
    k[j] = (j < n) ? bins_key[binb + j] : 0ull;
    id[j] = (u32)j;
    if (j < n) box[j] = bins_box[binb + j];
  }
  __syncthreads();
  for (int len = 2; len <= m; len <<= 1) {
    for (int str = len >> 1; str; str >>= 1) {
      for (int i = tid; i < (m >> 1); i += 256) {
        int a = 2 * str * (i / str) + (i % str);
        int c = a + str;
        bool desc = ((a & len) == 0);
        u64 ka = k[a], kc = k[c];
        if (desc ? (ka < kc) : (ka > kc)) {
          k[a] = kc; k[c] = ka;
          u32 t = id[a]; id[a] = id[c]; id[c] = t;
        }
      }
      __syncthreads();
    }
  }
  if (tid >= 64) return;  // waves 1-3 done; wave 0 continues barrier-free

  int lane = tid;
  int S = 0;
  for (int base = 0; base < n && S < NDET; base += 64) {
    int i = base + lane;
    bool have = (i < n);
    u64 mykey = 0ull;
    u32 myid = 0;
    float4 Bb = make_float4(0.f, 0.f, 0.f, 0.f);
    float aB = 0.f;
    if (have) {
      mykey = k[i];
      myid = id[i];
      float4 raw = box[myid];
      Bb = make_float4(raw.x + loff, raw.y + loff, raw.z + loff, raw.w + loff);
      aB = (Bb.z - Bb.x) * (Bb.w - Bb.y);
    }
    bool alive = have;
    for (int s = 0; s < S; ++s) {   // suppression by earlier-chunk survivors
      float4 A = s_sb[s];
      float aA = s_sa[s];
      float ix1 = fmaxf(A.x, Bb.x), iy1 = fmaxf(A.y, Bb.y);
      float ix2 = fminf(A.z, Bb.z), iy2 = fminf(A.w, Bb.w);
      float inter = fmaxf(ix2 - ix1, 0.0f) * fmaxf(iy2 - iy1, 0.0f);
      float iou = inter / fmaxf(aA + aB - inter, 1e-9f);
      if (alive && iou > 0.5f) alive = false;
    }
    u64 mask = __ballot(alive);
    while (mask && S < NDET) {
      int j = __builtin_ctzll(mask);
      float Ax = __shfl(Bb.x, j), Ay = __shfl(Bb.y, j);
      float Az = __shfl(Bb.z, j), Aw = __shfl(Bb.w, j);
      float aA = __shfl(aB, j);
      if (lane == j) {
        s_sb[S] = Bb; s_sa[S] = aB; s_sk[S] = mykey; s_sid[S] = myid;
      }
      float ix1 = fmaxf(Ax, Bb.x), iy1 = fmaxf(Ay, Bb.y);
      float ix2 = fminf(Az, Bb.z), iy2 = fminf(Aw, Bb.w);
      float inter = fmaxf(ix2 - ix1, 0.0f) * fmaxf(iy2 - iy1, 0.0f);
      float iou = inter / fmaxf(aA + aB - inter, 1e-9f);
      if (alive && iou > 0.5f) alive = false;  // selected lane leaves via IoU=1
      ++S;
      mask = __ballot(alive);
    }
  }
  if (S == 0) return;
  int basep = 0;
  if (lane == 0) basep = (int)atomicAdd(surv_cnt + b, (u32)S);
  basep = __shfl(basep, 0);
  for (int i2 = lane; i2 < S; i2 += 64) {
    u32 p = (u32)(basep + i2);
    if (p < SURVCAP) {
      skey[(size_t)b * SURVCAP + p] = s_sk[i2];
      sbox[(size_t)b * SURVCAP + p] = box[s_sid[i2]];
    }
  }
}

// Per-image exact top-NDET. Threshold T (100th-largest score bits) via
// contention-free 32-step bisection (register compares + shfl reduce; no
// LDS atomics -- clustered float exponents serialize histograms). Compact
// >T plus ==T ties, bitonic sort by full 54-bit key = reference order.
__global__ __launch_bounds__(256) void k_top(const u32* __restrict__ surv_cnt,
    const u64* __restrict__ skey, const float4* __restrict__ sbox, float* out) {
  __shared__ u32 ssc[SURVCAP];
  __shared__ u32 s_red[4];
  __shared__ u32 s_cnt[2];
  __shared__ u64 fk[FKCAP];
  __shared__ u32 fs[FKCAP];

  int b = blockIdx.x;
  int tid = threadIdx.x;
  u32 ns = surv_cnt[b];
  if (ns > SURVCAP) ns = SURVCAP;
  const u64* kb = skey + (size_t)b * SURVCAP;

  for (u32 j = tid; j < ns; j += 256) ssc[j] = (u32)(kb[j] >> 22);
  if (tid == 0) { s_cnt[0] = 0; s_cnt[1] = 0; }
  __syncthreads();

  u32 T = 0;
  if (ns > NDET) {
    u32 lo = 0, hi = 0xFFFFFFFFu;   // minimal x with count(s>x) < NDET
    while (lo < hi) {
      u32 mid = lo + ((hi - lo) >> 1);
      u32 c = 0;
      for (u32 j = tid; j < ns; j += 256) c += (ssc[j] > mid) ? 1u : 0u;
      for (int o = 32; o; o >>= 1) c += __shfl_xor(c, o);
      if ((tid & 63) == 0) s_red[tid >> 6] = c;
      __syncthreads();
      u32 totc = s_red[0] + s_red[1] + s_red[2] + s_red[3];
      __syncthreads();
      if (totc < NDET) hi = mid; else lo = mid + 1;
    }
    T = lo;
  }
  __syncthreads();

  for (u32 j = tid; j < ns; j += 256) {
    bool take = (ns <= NDET) || (ssc[j] > T);
    if (take) {
      u32 p = atomicAdd(&s_cnt[0], 1u);
      if (p < FKCAP) { fk[p] = kb[j]; fs[p] = j; }
    }
  }
  __syncthreads();
  if (tid == 0) s_cnt[1] = s_cnt[0];
  __syncthreads();
  if (ns > NDET) {  // append ==T ties; order fixed by full-key sort below
    for (u32 j = tid; j < ns; j += 256) {
      if (ssc[j] == T) {
        u32 p = atomicAdd(&s_cnt[1], 1u);
        if (p < FKCAP) { fk[p] = kb[j]; fs[p] = j; }
      }
    }
  }
  __syncthreads();
  u32 tot = s_cnt[1];
  if (tot > FKCAP) tot = FKCAP;
  u32 m2 = 1;
  while (m2 < tot) m2 <<= 1;
  if (m2 < 2) m2 = 2;
  for (u32 j = tot + tid; j < m2; j += 256) { fk[j] = 0ull; fs[j] = 0u; }
  __syncthreads();
  for (u32 len = 2; len <= m2; len <<= 1) {
    for (u32 str = len >> 1; str; str >>= 1) {
      for (u32 i = tid; i < (m2 >> 1); i += 256) {
        u32 a = 2 * str * (i / str) + (i % str);
        u32 c = a + str;
        bool desc = ((a & len) == 0);
        u64 ka = fk[a], kc = fk[c];
        if (desc ? (ka < kc) : (ka > kc)) {
          fk[a] = kc; fk[c] = ka;
          u32 t2 = fs[a]; fs[a] = fs[c]; fs[c] = t2;
        }
      }
      __syncthreads();
    }
  }
  // boxes[3200] | scores[800] | labels[800] | keep[800]
  if (tid < NDET) {
    u64 key = ((u32)tid < tot) ? fk[tid] : 0ull;
    float b0 = 0.f, b1 = 0.f, b2 = 0.f, b3 = 0.f, sc = 0.f, lb = 0.f, kp = 0.f;
    if (key) {
      float4 bx = sbox[(size_t)b * SURVCAP + fs[tid]];
      b0 = bx.x; b1 = bx.y; b2 = bx.z; b3 = bx.w;
      sc = __uint_as_float((u32)(key >> 22));
      u32 orig = 0x3FFFFFu - (u32)(key & 0x3FFFFFu);
      lb = (float)(orig % NCLS + 1u);
      kp = 1.0f;
    }
    float* ob = out + ((size_t)b * NDET + tid) * 4;
    ob[0] = b0; ob[1] = b1; ob[2] = b2; ob[3] = b3;
    out[NB * NDET * 4 + b * NDET + tid] = sc;
    out[NB * NDET * 5 + b * NDET + tid] = lb;
    out[NB * NDET * 6 + b * NDET + tid] = kp;
  }
}

// ---------------------------------------------------------------- launch ----
extern "C" void kernel_launch(void* const* d_in, const int* in_sizes, int n_in,
                              void* d_out, int out_size, void* d_ws, size_t ws_size,
                              hipStream_t stream) {
  const float* logits = (const float*)d_in[0];
  const float* boxreg = (const float*)d_in[1];
  const float* props  = (const float*)d_in[2];
  const int* dh = (const int*)d_in[3];
  const int* dw = (const int*)d_in[4];
  float* out = (float*)d_out;

  char* ws = (char*)d_ws;
  u32* bin_cnt  = (u32*)ws;                                   // 720*16 u32 = 45 KiB
  u32* surv_cnt = (u32*)(ws + 46080);                         // 8 u32
  u64* bins_key = (u64*)(ws + 46336);                         // 720*512*8  = 2.95 MB
  char* p1 = ws + 46336 + (size_t)NB * NCLS * BINCAP * 8;
  float4* bins_box = (float4*)p1;                             // 720*512*16 = 5.9 MB
  char* p2 = p1 + (size_t)NB * NCLS * BINCAP * 16;
  u64* skey = (u64*)p2;                                       // 8*9216*8 = 590 KB
  float4* sbox = (float4*)(p2 + (size_t)NB * SURVCAP * 8);    // 8*9216*16 = 1.18 MB
  (void)ws_size;

  k_zero<<<1, 1024, 0, stream>>>(bin_cnt, surv_cnt);
  k_score<<<NB * CHUNKS, 1024, 0, stream>>>(logits, boxreg, props, dh, dw,
                                            bin_cnt, bins_key, bins_box);
  k_nms_class<<<NB * NCLS, 256, 0, stream>>>(bin_cnt, bins_key, bins_box,
                                             surv_cnt, skey, sbox, dh, dw);
  k_top<<<NB, 256, 0, stream>>>(surv_cnt, skey, sbox, out);
}

// Round 7
// 195.778 us; speedup vs baseline: 1.1096x; 1.1096x over previous
//
#include <hip/hip_runtime.h>
#include <stdint.h>

typedef uint32_t u32;
typedef unsigned long long u64;

#define NB 8
#define NPER 4000
#define NC 91
#define NCLS 90
#define NDET 100
#define CHUNKS 32
#define RPB 125        // rows per k_score block = NPER/CHUNKS
#define LBIN 16        // LDS bin capacity per class per block (avg ~5.6 used)
#define BINCAP 512     // global bin capacity per (image,class); avg ~180
#define CSTRIDE 16     // u32 stride: one counter per 64B line (atomic serialization)
#define SURVCAP 9216   // >= 90*100
#define FKCAP 1024     // k_top final pool (100 + score ties)
#define VPT 9          // k_top values/thread = ceil(SURVCAP/1024)

// ---------------------------------------------------------------- decode ----
// bit-identical to reference op order (verified absmax 0.0 in R1-R6)
__device__ __forceinline__ float4 decode_clip(float4 rel, float w, float h,
                                              float cx, float cy, float W, float H) {
  const float XCLIP = 4.135166556742356f;  // log(1000/16)
  float dx = rel.x / 10.0f;
  float dy = rel.y / 10.0f;
  float dw = fminf(rel.z / 5.0f, XCLIP);
  float dh = fminf(rel.w / 5.0f, XCLIP);
  float qcx = dx * w + cx;
  float qcy = dy * h + cy;
  float qw = expf(dw) * w;
  float qh = expf(dh) * h;
  float x1 = qcx - 0.5f * qw, y1 = qcy - 0.5f * qh;
  float x2 = qcx + 0.5f * qw, y2 = qcy + 0.5f * qh;
  x1 = fminf(fmaxf(x1, 0.0f), W);
  x2 = fminf(fmaxf(x2, 0.0f), W);
  y1 = fminf(fmaxf(y1, 0.0f), H);
  y2 = fminf(fmaxf(y2, 0.0f), H);
  return make_float4(x1, y1, x2, y2);
}

// ---------------------------------------------------------------- kernels ---
__global__ __launch_bounds__(1024) void k_zero(u32* bin_cnt, u32* surv_cnt) {
  int t = threadIdx.x;
  for (int j = t; j < NB * NCLS * CSTRIDE; j += 1024) bin_cnt[j] = 0u;
  if (t < NB) surv_cnt[t] = 0u;
}

// Front-end: softmax + decode + filter in ONE pass. One wave per row; block
// covers 125 consecutive rows (boxreg gathers stay in a 182 KB L2-friendly
// window). Candidates failing MIN_SIZE are dropped here (== reference's
// valid-mask exclusion). Survive -> (key, decoded box) into LDS class bins,
// flushed cooperatively with one global atomic per non-empty class.
__global__ __launch_bounds__(1024) void k_score(const float* __restrict__ logits,
    const float* __restrict__ boxreg, const float* __restrict__ props,
    const int* __restrict__ dh, const int* __restrict__ dw,
    u32* bin_cnt, u64* bins_key, float4* bins_box) {
  __shared__ u64 s_key[NCLS][LBIN];
  __shared__ float4 s_box[NCLS][LBIN];
  __shared__ u32 s_cnt[NCLS];
  __shared__ u32 s_base[NCLS];
  __shared__ u32 s_cl[NCLS];
  int tid = threadIdx.x;
  int b = blockIdx.x / CHUNKS;
  int chunk = blockIdx.x % CHUNKS;
  int wave = tid >> 6, lane = tid & 63;
  if (tid < NCLS) s_cnt[tid] = 0u;
  __syncthreads();

  float H = (float)dh[0], W = (float)dw[0];
  const float4* props4 = (const float4*)props;
  const float4* breg4 = (const float4*)boxreg;

  for (int rloc = wave; rloc < RPB; rloc += 16) {
    int rl = chunk * RPB + rloc;
    int r = b * NPER + rl;
    const float* lrow = logits + (size_t)r * NC;
    float xA = lrow[lane];
    float xB = (lane < NC - 64) ? lrow[64 + lane] : -3.0e38f;
    float mx = fmaxf(xA, xB);
    for (int o = 32; o; o >>= 1) mx = fmaxf(mx, __shfl_xor(mx, o));
    float eA = expf(xA - mx);
    float eB = (lane < NC - 64) ? expf(xB - mx) : 0.0f;
    float sm = eA + eB;
    for (int o = 32; o; o >>= 1) sm += __shfl_xor(sm, o);
    float sA = eA / sm;
    float sB = eB / sm;
    bool eA_ok = (lane >= 1) && (sA > 0.05f);
    bool eB_ok = (lane < NC - 64) && (sB > 0.05f);
    if (eA_ok || eB_ok) {
      float4 p = props4[r];
      float w = p.z - p.x, h = p.w - p.y;
      float cx = p.x + 0.5f * w, cy = p.y + 0.5f * h;
      if (eA_ok) {
        float4 raw = decode_clip(breg4[(size_t)r * NC + lane], w, h, cx, cy, W, H);
        if (((raw.z - raw.x) >= 0.01f) && ((raw.w - raw.y) >= 0.01f)) {
          int ci = lane - 1;
          u32 orig = (u32)(rl * NCLS + ci);
          u64 key = ((u64)__float_as_uint(sA) << 22) | (u64)(0x3FFFFFu - orig);
          u32 lp = atomicAdd(&s_cnt[ci], 1u);
          if (lp < LBIN) { s_key[ci][lp] = key; s_box[ci][lp] = raw; }
          else {  // rare overflow: direct global (slot disjoint via same counter)
            u32 gp = atomicAdd(&bin_cnt[(b * NCLS + ci) * CSTRIDE], 1u);
            if (gp < BINCAP) {
              size_t o = ((size_t)b * NCLS + ci) * BINCAP + gp;
              bins_key[o] = key; bins_box[o] = raw;
            }
          }
        }
      }
      if (eB_ok) {
        float4 raw = decode_clip(breg4[(size_t)r * NC + 64 + lane], w, h, cx, cy, W, H);
        if (((raw.z - raw.x) >= 0.01f) && ((raw.w - raw.y) >= 0.01f)) {
          int ci = 63 + lane;
          u32 orig = (u32)(rl * NCLS + ci);
          u64 key = ((u64)__float_as_uint(sB) << 22) | (u64)(0x3FFFFFu - orig);
          u32 lp = atomicAdd(&s_cnt[ci], 1u);
          if (lp < LBIN) { s_key[ci][lp] = key; s_box[ci][lp] = raw; }
          else {
            u32 gp = atomicAdd(&bin_cnt[(b * NCLS + ci) * CSTRIDE], 1u);
            if (gp < BINCAP) {
              size_t o = ((size_t)b * NCLS + ci) * BINCAP + gp;
              bins_key[o] = key; bins_box[o] = raw;
            }
          }
        }
      }
    }
  }
  __syncthreads();
  if (tid < NCLS) {
    u32 cl = s_cnt[tid];
    if (cl > LBIN) cl = LBIN;
    s_cl[tid] = cl;
    s_base[tid] = cl ? atomicAdd(&bin_cnt[(b * NCLS + tid) * CSTRIDE], cl) : 0u;
  }
  __syncthreads();
  for (int idx = tid; idx < NCLS * LBIN; idx += 1024) {  // cooperative flush
    int ci = idx / LBIN, j = idx % LBIN;
    if ((u32)j < s_cl[ci]) {
      u32 p = s_base[ci] + (u32)j;
      if (p < BINCAP) {
        size_t o = ((size_t)b * NCLS + ci) * BINCAP + p;
        bins_key[o] = s_key[ci][j];
        bins_box[o] = s_box[ci][j];
      }
    }
  }
}

// Per-(image,class) greedy NMS. 256 threads: coalesced stage of keys+boxes
// into LDS, 4-wave bitonic sort (key,id), then waves 1-3 retire and wave 0
// runs ballot-greedy entirely LDS-resident with NO barriers.
__global__ __launch_bounds__(256) void k_nms_class(const u32* __restrict__ bin_cnt,
    const u64* __restrict__ bins_key, const float4* __restrict__ bins_box,
    u32* surv_cnt, u64* skey, float4* sbox,
    const int* __restrict__ dh, const int* __restrict__ dw) {
  __shared__ u64 k[BINCAP];
  __shared__ u32 id[BINCAP];
  __shared__ float4 box[BINCAP];
  __shared__ float4 s_sb[NDET];   // survivor offset boxes (IoU space)
  __shared__ float s_sa[NDET];
  __shared__ u64 s_sk[NDET];
  __shared__ u32 s_sid[NDET];

  int b = blockIdx.x / NCLS;
  int ci = blockIdx.x % NCLS;
  u32 cnt = bin_cnt[(b * NCLS + ci) * CSTRIDE];
  int n = (int)((cnt < BINCAP) ? cnt : BINCAP);
  if (n <= 0) return;

  int tid = threadIdx.x;
  float H = (float)dh[0], W = (float)dw[0];
  float loff = (fmaxf(H, W) + 1.0f) * (float)(ci + 1);
  size_t binb = ((size_t)b * NCLS + ci) * BINCAP;

  int m = 1;
  while (m < n) m <<= 1;
  if (m < 2) m = 2;
  for (int j = tid; j < m; j += 256) {
    k[j] = (j < n) ? bins_key[binb + j] : 0ull;
    id[j] = (u32)j;
    if (j < n) box[j] = bins_box[binb + j];
  }
  __syncthreads();
  for (int len = 2; len <= m; len <<= 1) {
    for (int str = len >> 1; str; str >>= 1) {
      for (int i = tid; i < (m >> 1); i += 256) {
        int a = 2 * str * (i / str) + (i % str);
        int c = a + str;
        bool desc = ((a & len) == 0);
        u64 ka = k[a], kc = k[c];
        if (desc ? (ka < kc) : (ka > kc)) {
          k[a] = kc; k[c] = ka;
          u32 t = id[a]; id[a] = id[c]; id[c] = t;
        }
      }
      __syncthreads();
    }
  }
  if (tid >= 64) return;  // waves 1-3 done; wave 0 continues barrier-free

  int lane = tid;
  int S = 0;
  for (int base = 0; base < n && S < NDET; base += 64) {
    int i = base + lane;
    bool have = (i < n);
    u64 mykey = 0ull;
    u32 myid = 0;
    float4 Bb = make_float4(0.f, 0.f, 0.f, 0.f);
    float aB = 0.f;
    if (have) {
      mykey = k[i];
      myid = id[i];
      float4 raw = box[myid];
      Bb = make_float4(raw.x + loff, raw.y + loff, raw.z + loff, raw.w + loff);
      aB = (Bb.z - Bb.x) * (Bb.w - Bb.y);
    }
    bool alive = have;
    for (int s = 0; s < S; ++s) {   // suppression by earlier-chunk survivors
      float4 A = s_sb[s];
      float aA = s_sa[s];
      float ix1 = fmaxf(A.x, Bb.x), iy1 = fmaxf(A.y, Bb.y);
      float ix2 = fminf(A.z, Bb.z), iy2 = fminf(A.w, Bb.w);
      float inter = fmaxf(ix2 - ix1, 0.0f) * fmaxf(iy2 - iy1, 0.0f);
      float iou = inter / fmaxf(aA + aB - inter, 1e-9f);
      if (alive && iou > 0.5f) alive = false;
    }
    u64 mask = __ballot(alive);
    while (mask && S < NDET) {
      int j = __builtin_ctzll(mask);
      float Ax = __shfl(Bb.x, j), Ay = __shfl(Bb.y, j);
      float Az = __shfl(Bb.z, j), Aw = __shfl(Bb.w, j);
      float aA = __shfl(aB, j);
      if (lane == j) {
        s_sb[S] = Bb; s_sa[S] = aB; s_sk[S] = mykey; s_sid[S] = myid;
      }
      float ix1 = fmaxf(Ax, Bb.x), iy1 = fmaxf(Ay, Bb.y);
      float ix2 = fminf(Az, Bb.z), iy2 = fminf(Aw, Bb.w);
      float inter = fmaxf(ix2 - ix1, 0.0f) * fmaxf(iy2 - iy1, 0.0f);
      float iou = inter / fmaxf(aA + aB - inter, 1e-9f);
      if (alive && iou > 0.5f) alive = false;  // selected lane leaves via IoU=1
      ++S;
      mask = __ballot(alive);
    }
  }
  if (S == 0) return;
  int basep = 0;
  if (lane == 0) basep = (int)atomicAdd(surv_cnt + b, (u32)S);
  basep = __shfl(basep, 0);
  for (int i2 = lane; i2 < S; i2 += 64) {
    u32 p = (u32)(basep + i2);
    if (p < SURVCAP) {
      skey[(size_t)b * SURVCAP + p] = s_sk[i2];
      sbox[(size_t)b * SURVCAP + p] = box[s_sid[i2]];
    }
  }
}

// Per-image exact top-NDET. Scores hoisted into REGISTERS (VPT=9/thread,
// 1024 threads) so the 32-step bisection for the 100th-largest score T is
// pure register compares + shfl reduce -- no LDS in the loop (R6's 55 us
// was a per-iteration ds_read latency chain). Compact >T plus ==T ties,
// bitonic sort by full 54-bit key = exact reference selection order.
__global__ __launch_bounds__(1024) void k_top(const u32* __restrict__ surv_cnt,
    const u64* __restrict__ skey, const float4* __restrict__ sbox, float* out) {
  __shared__ u32 ssc[SURVCAP];
  __shared__ u32 s_red[16];
  __shared__ u32 s_cnt[2];
  __shared__ u64 fk[FKCAP];
  __shared__ u32 fs[FKCAP];

  int b = blockIdx.x;
  int tid = threadIdx.x;
  u32 ns = surv_cnt[b];
  if (ns > SURVCAP) ns = SURVCAP;
  const u64* kb = skey + (size_t)b * SURVCAP;

  u32 sc[VPT];
#pragma unroll
  for (int v = 0; v < VPT; ++v) {
    u32 j = (u32)tid + (u32)v * 1024u;
    u32 s = 0u;
    if (j < ns) s = (u32)(kb[j] >> 22);
    sc[v] = s;
    if (j < SURVCAP) ssc[j] = s;
  }
  if (tid == 0) { s_cnt[0] = 0; s_cnt[1] = 0; }
  __syncthreads();

  u32 T = 0;
  if (ns > NDET) {
    u32 lo = 0, hi = 0xFFFFFFFFu;   // minimal x with count(s>x) < NDET
    while (lo < hi) {
      u32 mid = lo + ((hi - lo) >> 1);
      u32 c = 0;
#pragma unroll
      for (int v = 0; v < VPT; ++v) c += (sc[v] > mid) ? 1u : 0u;
      for (int o = 32; o; o >>= 1) c += __shfl_xor(c, o);
      if ((tid & 63) == 0) s_red[tid >> 6] = c;
      __syncthreads();
      u32 totc = 0;
#pragma unroll
      for (int w = 0; w < 16; ++w) totc += s_red[w];  // broadcast reads
      __syncthreads();
      if (totc < NDET) hi = mid; else lo = mid + 1;
    }
    T = lo;
  }
  __syncthreads();

  for (u32 j = tid; j < ns; j += 1024) {
    bool take = (ns <= NDET) || (ssc[j] > T);
    if (take) {
      u32 p = atomicAdd(&s_cnt[0], 1u);
      if (p < FKCAP) { fk[p] = kb[j]; fs[p] = j; }
    }
  }
  __syncthreads();
  if (tid == 0) s_cnt[1] = s_cnt[0];
  __syncthreads();
  if (ns > NDET) {  // append ==T ties; order fixed by full-key sort below
    for (u32 j = tid; j < ns; j += 1024) {
      if (ssc[j] == T) {
        u32 p = atomicAdd(&s_cnt[1], 1u);
        if (p < FKCAP) { fk[p] = kb[j]; fs[p] = j; }
      }
    }
  }
  __syncthreads();
  u32 tot = s_cnt[1];
  if (tot > FKCAP) tot = FKCAP;
  u32 m2 = 1;
  while (m2 < tot) m2 <<= 1;
  if (m2 < 2) m2 = 2;
  for (u32 j = tot + tid; j < m2; j += 1024) { fk[j] = 0ull; fs[j] = 0u; }
  __syncthreads();
  for (u32 len = 2; len <= m2; len <<= 1) {
    for (u32 str = len >> 1; str; str >>= 1) {
      for (u32 i = tid; i < (m2 >> 1); i += 1024) {
        u32 a = 2 * str * (i / str) + (i % str);
        u32 c = a + str;
        bool desc = ((a & len) == 0);
        u64 ka = fk[a], kc = fk[c];
        if (desc ? (ka < kc) : (ka > kc)) {
          fk[a] = kc; fk[c] = ka;
          u32 t2 = fs[a]; fs[a] = fs[c]; fs[c] = t2;
        }
      }
      __syncthreads();
    }
  }
  // boxes[3200] | scores[800] | labels[800] | keep[800]
  if (tid < NDET) {
    u64 key = ((u32)tid < tot) ? fk[tid] : 0ull;
    float b0 = 0.f, b1 = 0.f, b2 = 0.f, b3 = 0.f, sc2 = 0.f, lb = 0.f, kp = 0.f;
    if (key) {
      float4 bx = sbox[(size_t)b * SURVCAP + fs[tid]];
      b0 = bx.x; b1 = bx.y; b2 = bx.z; b3 = bx.w;
      sc2 = __uint_as_float((u32)(key >> 22));
      u32 orig = 0x3FFFFFu - (u32)(key & 0x3FFFFFu);
      lb = (float)(orig % NCLS + 1u);
      kp = 1.0f;
    }
    float* ob = out + ((size_t)b * NDET + tid) * 4;
    ob[0] = b0; ob[1] = b1; ob[2] = b2; ob[3] = b3;
    out[NB * NDET * 4 + b * NDET + tid] = sc2;
    out[NB * NDET * 5 + b * NDET + tid] = lb;
    out[NB * NDET * 6 + b * NDET + tid] = kp;
  }
}

// ---------------------------------------------------------------- launch ----
extern "C" void kernel_launch(void* const* d_in, const int* in_sizes, int n_in,
                              void* d_out, int out_size, void* d_ws, size_t ws_size,
                              hipStream_t stream) {
  const float* logits = (const float*)d_in[0];
  const float* boxreg = (const float*)d_in[1];
  const float* props  = (const float*)d_in[2];
  const int* dh = (const int*)d_in[3];
  const int* dw = (const int*)d_in[4];
  float* out = (float*)d_out;

  char* ws = (char*)d_ws;
  u32* bin_cnt  = (u32*)ws;                                   // 720*16 u32 = 45 KiB
  u32* surv_cnt = (u32*)(ws + 46080);                         // 8 u32
  u64* bins_key = (u64*)(ws + 46336);                         // 720*512*8  = 2.95 MB
  char* p1 = ws + 46336 + (size_t)NB * NCLS * BINCAP * 8;
  float4* bins_box = (float4*)p1;                             // 720*512*16 = 5.9 MB
  char* p2 = p1 + (size_t)NB * NCLS * BINCAP * 16;
  u64* skey = (u64*)p2;                                       // 8*9216*8 = 590 KB
  float4* sbox = (float4*)(p2 + (size_t)NB * SURVCAP * 8);    // 8*9216*16 = 1.18 MB
  (void)ws_size;

  k_zero<<<1, 1024, 0, stream>>>(bin_cnt, surv_cnt);
  k_score<<<NB * CHUNKS, 1024, 0, stream>>>(logits, boxreg, props, dh, dw,
                                            bin_cnt, bins_key, bins_box);
  k_nms_class<<<NB * NCLS, 256, 0, stream>>>(bin_cnt, bins_key, bins_box,
                                             surv_cnt, skey, sbox, dh, dw);
  k_top<<<NB, 1024, 0, stream>>>(surv_cnt, skey, sbox, out);
}

// Round 8
// 188.833 us; speedup vs baseline: 1.1504x; 1.0368x over previous
//
#include <hip/hip_runtime.h>
#include <stdint.h>

typedef uint32_t u32;
typedef unsigned long long u64;

#define NB 8
#define NPER 4000
#define NC 91
#define NCLS 90
#define NDET 100
#define CHUNKS 32
#define RPB 125        // rows per k_score block = NPER/CHUNKS
#define LBIN 16        // LDS bin capacity per class per block (avg ~5.6 used)
#define BINCAP 512     // global bin capacity per (image,class); avg ~100
#define CSTRIDE 16     // u32 stride: one counter per 64B line (atomic serialization)
#define SURVCAP 9216   // >= 90*100
#define FKCAP 1024     // k_top final pool (100 + score ties)
#define VPT 9          // k_top values/thread = ceil(SURVCAP/1024)

// ---------------------------------------------------------------- decode ----
// bit-identical to reference op order (verified absmax 0.0 in R1-R7)
__device__ __forceinline__ float4 decode_clip(float4 rel, float w, float h,
                                              float cx, float cy, float W, float H) {
  const float XCLIP = 4.135166556742356f;  // log(1000/16)
  float dx = rel.x / 10.0f;
  float dy = rel.y / 10.0f;
  float dw = fminf(rel.z / 5.0f, XCLIP);
  float dh = fminf(rel.w / 5.0f, XCLIP);
  float qcx = dx * w + cx;
  float qcy = dy * h + cy;
  float qw = expf(dw) * w;
  float qh = expf(dh) * h;
  float x1 = qcx - 0.5f * qw, y1 = qcy - 0.5f * qh;
  float x2 = qcx + 0.5f * qw, y2 = qcy + 0.5f * qh;
  x1 = fminf(fmaxf(x1, 0.0f), W);
  x2 = fminf(fmaxf(x2, 0.0f), W);
  y1 = fminf(fmaxf(y1, 0.0f), H);
  y2 = fminf(fmaxf(y2, 0.0f), H);
  return make_float4(x1, y1, x2, y2);
}

// ---------------------------------------------------------------- kernels ---
__global__ __launch_bounds__(1024) void k_zero(u32* bin_cnt, u32* surv_cnt) {
  int t = threadIdx.x;
  for (int j = t; j < NB * NCLS * CSTRIDE; j += 1024) bin_cnt[j] = 0u;
  if (t < NB) surv_cnt[t] = 0u;
}

// Front-end: softmax + decode + filter in ONE pass. One wave per row; block
// covers 125 consecutive rows (boxreg gathers stay in a 182 KB L2-friendly
// window). Candidates failing MIN_SIZE are dropped here (== reference's
// valid-mask exclusion). Survive -> (key, decoded box) into LDS class bins,
// flushed cooperatively with one global atomic per non-empty class.
__global__ __launch_bounds__(1024) void k_score(const float* __restrict__ logits,
    const float* __restrict__ boxreg, const float* __restrict__ props,
    const int* __restrict__ dh, const int* __restrict__ dw,
    u32* bin_cnt, u64* bins_key, float4* bins_box) {
  __shared__ u64 s_key[NCLS][LBIN];
  __shared__ float4 s_box[NCLS][LBIN];
  __shared__ u32 s_cnt[NCLS];
  __shared__ u32 s_base[NCLS];
  __shared__ u32 s_cl[NCLS];
  int tid = threadIdx.x;
  int b = blockIdx.x / CHUNKS;
  int chunk = blockIdx.x % CHUNKS;
  int wave = tid >> 6, lane = tid & 63;
  if (tid < NCLS) s_cnt[tid] = 0u;
  __syncthreads();

  float H = (float)dh[0], W = (float)dw[0];
  const float4* props4 = (const float4*)props;
  const float4* breg4 = (const float4*)boxreg;

  for (int rloc = wave; rloc < RPB; rloc += 16) {
    int rl = chunk * RPB + rloc;
    int r = b * NPER + rl;
    const float* lrow = logits + (size_t)r * NC;
    float xA = lrow[lane];
    float xB = (lane < NC - 64) ? lrow[64 + lane] : -3.0e38f;
    float mx = fmaxf(xA, xB);
    for (int o = 32; o; o >>= 1) mx = fmaxf(mx, __shfl_xor(mx, o));
    float eA = expf(xA - mx);
    float eB = (lane < NC - 64) ? expf(xB - mx) : 0.0f;
    float sm = eA + eB;
    for (int o = 32; o; o >>= 1) sm += __shfl_xor(sm, o);
    float sA = eA / sm;
    float sB = eB / sm;
    bool eA_ok = (lane >= 1) && (sA > 0.05f);
    bool eB_ok = (lane < NC - 64) && (sB > 0.05f);
    if (eA_ok || eB_ok) {
      float4 p = props4[r];
      float w = p.z - p.x, h = p.w - p.y;
      float cx = p.x + 0.5f * w, cy = p.y + 0.5f * h;
      if (eA_ok) {
        float4 raw = decode_clip(breg4[(size_t)r * NC + lane], w, h, cx, cy, W, H);
        if (((raw.z - raw.x) >= 0.01f) && ((raw.w - raw.y) >= 0.01f)) {
          int ci = lane - 1;
          u32 orig = (u32)(rl * NCLS + ci);
          u64 key = ((u64)__float_as_uint(sA) << 22) | (u64)(0x3FFFFFu - orig);
          u32 lp = atomicAdd(&s_cnt[ci], 1u);
          if (lp < LBIN) { s_key[ci][lp] = key; s_box[ci][lp] = raw; }
          else {  // rare overflow: direct global (slot disjoint via same counter)
            u32 gp = atomicAdd(&bin_cnt[(b * NCLS + ci) * CSTRIDE], 1u);
            if (gp < BINCAP) {
              size_t o = ((size_t)b * NCLS + ci) * BINCAP + gp;
              bins_key[o] = key; bins_box[o] = raw;
            }
          }
        }
      }
      if (eB_ok) {
        float4 raw = decode_clip(breg4[(size_t)r * NC + 64 + lane], w, h, cx, cy, W, H);
        if (((raw.z - raw.x) >= 0.01f) && ((raw.w - raw.y) >= 0.01f)) {
          int ci = 63 + lane;
          u32 orig = (u32)(rl * NCLS + ci);
          u64 key = ((u64)__float_as_uint(sB) << 22) | (u64)(0x3FFFFFu - orig);
          u32 lp = atomicAdd(&s_cnt[ci], 1u);
          if (lp < LBIN) { s_key[ci][lp] = key; s_box[ci][lp] = raw; }
          else {
            u32 gp = atomicAdd(&bin_cnt[(b * NCLS + ci) * CSTRIDE], 1u);
            if (gp < BINCAP) {
              size_t o = ((size_t)b * NCLS + ci) * BINCAP + gp;
              bins_key[o] = key; bins_box[o] = raw;
            }
          }
        }
      }
    }
  }
  __syncthreads();
  if (tid < NCLS) {
    u32 cl = s_cnt[tid];
    if (cl > LBIN) cl = LBIN;
    s_cl[tid] = cl;
    s_base[tid] = cl ? atomicAdd(&bin_cnt[(b * NCLS + tid) * CSTRIDE], cl) : 0u;
  }
  __syncthreads();
  for (int idx = tid; idx < NCLS * LBIN; idx += 1024) {  // cooperative flush
    int ci = idx / LBIN, j = idx % LBIN;
    if ((u32)j < s_cl[ci]) {
      u32 p = s_base[ci] + (u32)j;
      if (p < BINCAP) {
        size_t o = ((size_t)b * NCLS + ci) * BINCAP + p;
        bins_key[o] = s_key[ci][j];
        bins_box[o] = s_box[ci][j];
      }
    }
  }
}

// Per-(image,class) greedy NMS. RANK SORT replaces bitonic (R7: 612K LDS
// bank-conflict cycles + ~32 barrier-laden stages were the critical path):
// keys are unique (orig disambiguates), so rank_i = #{j: k[j] > k[i]} is an
// exact permutation. The rank loop reads the SAME k[j] across the wave ->
// LDS broadcast, conflict-free, no barriers, loads pipeline. Keys AND boxes
// scattered into sorted arrays (kills the id[] indirection in the greedy).
// Then waves 1-3 retire; wave 0 runs ballot-greedy barrier-free.
__global__ __launch_bounds__(256) void k_nms_class(const u32* __restrict__ bin_cnt,
    const u64* __restrict__ bins_key, const float4* __restrict__ bins_box,
    u32* surv_cnt, u64* skey, float4* sbox,
    const int* __restrict__ dh, const int* __restrict__ dw) {
  __shared__ u64 k[BINCAP];       // unsorted keys
  __shared__ u64 ks[BINCAP];      // rank-sorted keys (desc)
  __shared__ float4 boxs[BINCAP]; // rank-sorted raw boxes
  __shared__ float4 s_sb[NDET];   // survivor offset boxes (IoU space)
  __shared__ float s_sa[NDET];
  __shared__ u64 s_sk[NDET];
  __shared__ u32 s_sid[NDET];     // survivor sorted-index

  int b = blockIdx.x / NCLS;
  int ci = blockIdx.x % NCLS;
  u32 cnt = bin_cnt[(b * NCLS + ci) * CSTRIDE];
  int n = (int)((cnt < BINCAP) ? cnt : BINCAP);
  if (n <= 0) return;

  int tid = threadIdx.x;
  float H = (float)dh[0], W = (float)dw[0];
  float loff = (fmaxf(H, W) + 1.0f) * (float)(ci + 1);
  size_t binb = ((size_t)b * NCLS + ci) * BINCAP;

  for (int j = tid; j < n; j += 256) k[j] = bins_key[binb + j];
  __syncthreads();
  for (int i = tid; i < n; i += 256) {
    u64 ki = k[i];
    u32 rank = 0;
    int j = 0;
    for (; j + 4 <= n; j += 4) {   // LDS broadcast reads, pipelined
      rank += (k[j] > ki) ? 1u : 0u;
      rank += (k[j + 1] > ki) ? 1u : 0u;
      rank += (k[j + 2] > ki) ? 1u : 0u;
      rank += (k[j + 3] > ki) ? 1u : 0u;
    }
    for (; j < n; ++j) rank += (k[j] > ki) ? 1u : 0u;
    ks[rank] = ki;
    boxs[rank] = bins_box[binb + i];
  }
  __syncthreads();
  if (tid >= 64) return;  // waves 1-3 done; wave 0 continues barrier-free

  int lane = tid;
  int S = 0;
  for (int base = 0; base < n && S < NDET; base += 64) {
    int i = base + lane;
    bool have = (i < n);
    u64 mykey = 0ull;
    float4 Bb = make_float4(0.f, 0.f, 0.f, 0.f);
    float aB = 0.f;
    if (have) {
      mykey = ks[i];
      float4 raw = boxs[i];
      Bb = make_float4(raw.x + loff, raw.y + loff, raw.z + loff, raw.w + loff);
      aB = (Bb.z - Bb.x) * (Bb.w - Bb.y);
    }
    bool alive = have;
    for (int s = 0; s < S; ++s) {   // suppression by earlier-chunk survivors
      float4 A = s_sb[s];
      float aA = s_sa[s];
      float ix1 = fmaxf(A.x, Bb.x), iy1 = fmaxf(A.y, Bb.y);
      float ix2 = fminf(A.z, Bb.z), iy2 = fminf(A.w, Bb.w);
      float inter = fmaxf(ix2 - ix1, 0.0f) * fmaxf(iy2 - iy1, 0.0f);
      float iou = inter / fmaxf(aA + aB - inter, 1e-9f);
      if (alive && iou > 0.5f) alive = false;
    }
    u64 mask = __ballot(alive);
    while (mask && S < NDET) {
      int j = __builtin_ctzll(mask);
      float Ax = __shfl(Bb.x, j), Ay = __shfl(Bb.y, j);
      float Az = __shfl(Bb.z, j), Aw = __shfl(Bb.w, j);
      float aA = __shfl(aB, j);
      if (lane == j) {
        s_sb[S] = Bb; s_sa[S] = aB; s_sk[S] = mykey; s_sid[S] = (u32)i;
      }
      float ix1 = fmaxf(Ax, Bb.x), iy1 = fmaxf(Ay, Bb.y);
      float ix2 = fminf(Az, Bb.z), iy2 = fminf(Aw, Bb.w);
      float inter = fmaxf(ix2 - ix1, 0.0f) * fmaxf(iy2 - iy1, 0.0f);
      float iou = inter / fmaxf(aA + aB - inter, 1e-9f);
      if (alive && iou > 0.5f) alive = false;  // selected lane leaves via IoU=1
      ++S;
      mask = __ballot(alive);
    }
  }
  if (S == 0) return;
  int basep = 0;
  if (lane == 0) basep = (int)atomicAdd(surv_cnt + b, (u32)S);
  basep = __shfl(basep, 0);
  for (int i2 = lane; i2 < S; i2 += 64) {
    u32 p = (u32)(basep + i2);
    if (p < SURVCAP) {
      skey[(size_t)b * SURVCAP + p] = s_sk[i2];
      sbox[(size_t)b * SURVCAP + p] = boxs[s_sid[i2]];
    }
  }
}

// Per-image exact top-NDET. Scores hoisted into REGISTERS (VPT=9/thread,
// 1024 threads) so the 32-step bisection for the 100th-largest score T is
// pure register compares + shfl reduce -- no LDS in the loop. Compact >T
// plus ==T ties, bitonic sort by full 54-bit key = reference order.
__global__ __launch_bounds__(1024) void k_top(const u32* __restrict__ surv_cnt,
    const u64* __restrict__ skey, const float4* __restrict__ sbox, float* out) {
  __shared__ u32 ssc[SURVCAP];
  __shared__ u32 s_red[16];
  __shared__ u32 s_cnt[2];
  __shared__ u64 fk[FKCAP];
  __shared__ u32 fs[FKCAP];

  int b = blockIdx.x;
  int tid = threadIdx.x;
  u32 ns = surv_cnt[b];
  if (ns > SURVCAP) ns = SURVCAP;
  const u64* kb = skey + (size_t)b * SURVCAP;

  u32 sc[VPT];
#pragma unroll
  for (int v = 0; v < VPT; ++v) {
    u32 j = (u32)tid + (u32)v * 1024u;
    u32 s = 0u;
    if (j < ns) s = (u32)(kb[j] >> 22);
    sc[v] = s;
    if (j < SURVCAP) ssc[j] = s;
  }
  if (tid == 0) { s_cnt[0] = 0; s_cnt[1] = 0; }
  __syncthreads();

  u32 T = 0;
  if (ns > NDET) {
    u32 lo = 0, hi = 0xFFFFFFFFu;   // minimal x with count(s>x) < NDET
    while (lo < hi) {
      u32 mid = lo + ((hi - lo) >> 1);
      u32 c = 0;
#pragma unroll
      for (int v = 0; v < VPT; ++v) c += (sc[v] > mid) ? 1u : 0u;
      for (int o = 32; o; o >>= 1) c += __shfl_xor(c, o);
      if ((tid & 63) == 0) s_red[tid >> 6] = c;
      __syncthreads();
      u32 totc = 0;
#pragma unroll
      for (int w = 0; w < 16; ++w) totc += s_red[w];  // broadcast reads
      __syncthreads();
      if (totc < NDET) hi = mid; else lo = mid + 1;
    }
    T = lo;
  }
  __syncthreads();

  for (u32 j = tid; j < ns; j += 1024) {
    bool take = (ns <= NDET) || (ssc[j] > T);
    if (take) {
      u32 p = atomicAdd(&s_cnt[0], 1u);
      if (p < FKCAP) { fk[p] = kb[j]; fs[p] = j; }
    }
  }
  __syncthreads();
  if (tid == 0) s_cnt[1] = s_cnt[0];
  __syncthreads();
  if (ns > NDET) {  // append ==T ties; order fixed by full-key sort below
    for (u32 j = tid; j < ns; j += 1024) {
      if (ssc[j] == T) {
        u32 p = atomicAdd(&s_cnt[1], 1u);
        if (p < FKCAP) { fk[p] = kb[j]; fs[p] = j; }
      }
    }
  }
  __syncthreads();
  u32 tot = s_cnt[1];
  if (tot > FKCAP) tot = FKCAP;
  u32 m2 = 1;
  while (m2 < tot) m2 <<= 1;
  if (m2 < 2) m2 = 2;
  for (u32 j = tot + tid; j < m2; j += 1024) { fk[j] = 0ull; fs[j] = 0u; }
  __syncthreads();
  for (u32 len = 2; len <= m2; len <<= 1) {
    for (u32 str = len >> 1; str; str >>= 1) {
      for (u32 i = tid; i < (m2 >> 1); i += 1024) {
        u32 a = 2 * str * (i / str) + (i % str);
        u32 c = a + str;
        bool desc = ((a & len) == 0);
        u64 ka = fk[a], kc = fk[c];
        if (desc ? (ka < kc) : (ka > kc)) {
          fk[a] = kc; fk[c] = ka;
          u32 t2 = fs[a]; fs[a] = fs[c]; fs[c] = t2;
        }
      }
      __syncthreads();
    }
  }
  // boxes[3200] | scores[800] | labels[800] | keep[800]
  if (tid < NDET) {
    u64 key = ((u32)tid < tot) ? fk[tid] : 0ull;
    float b0 = 0.f, b1 = 0.f, b2 = 0.f, b3 = 0.f, sc2 = 0.f, lb = 0.f, kp = 0.f;
    if (key) {
      float4 bx = sbox[(size_t)b * SURVCAP + fs[tid]];
      b0 = bx.x; b1 = bx.y; b2 = bx.z; b3 = bx.w;
      sc2 = __uint_as_float((u32)(key >> 22));
      u32 orig = 0x3FFFFFu - (u32)(key & 0x3FFFFFu);
      lb = (float)(orig % NCLS + 1u);
      kp = 1.0f;
    }
    float* ob = out + ((size_t)b * NDET + tid) * 4;
    ob[0] = b0; ob[1] = b1; ob[2] = b2; ob[3] = b3;
    out[NB * NDET * 4 + b * NDET + tid] = sc2;
    out[NB * NDET * 5 + b * NDET + tid] = lb;
    out[NB * NDET * 6 + b * NDET + tid] = kp;
  }
}

// ---------------------------------------------------------------- launch ----
extern "C" void kernel_launch(void* const* d_in, const int* in_sizes, int n_in,
                              void* d_out, int out_size, void* d_ws, size_t ws_size,
                              hipStream_t stream) {
  const float* logits = (const float*)d_in[0];
  const float* boxreg = (const float*)d_in[1];
  const float* props  = (const float*)d_in[2];
  const int* dh = (const int*)d_in[3];
  const int* dw = (const int*)d_in[4];
  float* out = (float*)d_out;

  char* ws = (char*)d_ws;
  u32* bin_cnt  = (u32*)ws;                                   // 720*16 u32 = 45 KiB
  u32* surv_cnt = (u32*)(ws + 46080);                         // 8 u32
  u64* bins_key = (u64*)(ws + 46336);                         // 720*512*8  = 2.95 MB
  char* p1 = ws + 46336 + (size_t)NB * NCLS * BINCAP * 8;
  float4* bins_box = (float4*)p1;                             // 720*512*16 = 5.9 MB
  char* p2 = p1 + (size_t)NB * NCLS * BINCAP * 16;
  u64* skey = (u64*)p2;                                       // 8*9216*8 = 590 KB
  float4* sbox = (float4*)(p2 + (size_t)NB * SURVCAP * 8);    // 8*9216*16 = 1.18 MB
  (void)ws_size;

  k_zero<<<1, 1024, 0, stream>>>(bin_cnt, surv_cnt);
  k_score<<<NB * CHUNKS, 1024, 0, stream>>>(logits, boxreg, props, dh, dw,
                                            bin_cnt, bins_key, bins_box);
  k_nms_class<<<NB * NCLS, 256, 0, stream>>>(bin_cnt, bins_key, bins_box,
                                             surv_cnt, skey, sbox, dh, dw);
  k_top<<<NB, 1024, 0, stream>>>(surv_cnt, skey, sbox, out);
}

// Round 9
// 188.320 us; speedup vs baseline: 1.1536x; 1.0027x over previous
//
#include <hip/hip_runtime.h>
#include <stdint.h>

typedef uint32_t u32;
typedef unsigned long long u64;

#define NB 8
#define NPER 4000
#define NC 91
#define NCLS 90
#define NDET 100
#define CHUNKS 64
#define RPB 63         // rows per k_score block = ceil(NPER/CHUNKS); guard rl<NPER
#define LBIN 16        // LDS bin capacity per class per block
#define BINCAP 512     // global bin capacity per (image,class); avg ~100
#define CSTRIDE 16     // u32 stride: one counter per 64B line (atomic serialization)
#define SURVCAP 9216   // >= 90*100
#define FKCAP 1024     // k_top compacted pool (100 + score ties)
#define VPT 36         // k_top values/thread = SURVCAP/256

// ---------------------------------------------------------------- decode ----
// bit-identical to reference op order (verified absmax 0.0 in R1-R8)
__device__ __forceinline__ float4 decode_clip(float4 rel, float w, float h,
                                              float cx, float cy, float W, float H) {
  const float XCLIP = 4.135166556742356f;  // log(1000/16)
  float dx = rel.x / 10.0f;
  float dy = rel.y / 10.0f;
  float dw = fminf(rel.z / 5.0f, XCLIP);
  float dh = fminf(rel.w / 5.0f, XCLIP);
  float qcx = dx * w + cx;
  float qcy = dy * h + cy;
  float qw = expf(dw) * w;
  float qh = expf(dh) * h;
  float x1 = qcx - 0.5f * qw, y1 = qcy - 0.5f * qh;
  float x2 = qcx + 0.5f * qw, y2 = qcy + 0.5f * qh;
  x1 = fminf(fmaxf(x1, 0.0f), W);
  x2 = fminf(fmaxf(x2, 0.0f), W);
  y1 = fminf(fmaxf(y1, 0.0f), H);
  y2 = fminf(fmaxf(y2, 0.0f), H);
  return make_float4(x1, y1, x2, y2);
}

// ---------------------------------------------------------------- kernels ---
__global__ __launch_bounds__(1024) void k_zero(u32* bin_cnt, u32* surv_cnt) {
  int t = threadIdx.x;
  for (int j = t; j < NB * NCLS * CSTRIDE; j += 1024) bin_cnt[j] = 0u;
  if (t < NB) surv_cnt[t] = 0u;
}

// Front-end: softmax + decode + filter in ONE pass. One wave per row; block
// covers 63 consecutive rows (CHUNKS=64 -> 2 blocks/CU, 8 waves/SIMD for
// latency hiding on the load->shfl-reduce->exp chains). MIN_SIZE failures
// dropped here (== reference's valid-mask exclusion). Survivors ->
// (key, decoded box) into LDS class bins, flushed cooperatively with one
// global atomic per non-empty class.
__global__ __launch_bounds__(1024) void k_score(const float* __restrict__ logits,
    const float* __restrict__ boxreg, const float* __restrict__ props,
    const int* __restrict__ dh, const int* __restrict__ dw,
    u32* bin_cnt, u64* bins_key, float4* bins_box) {
  __shared__ u64 s_key[NCLS][LBIN];
  __shared__ float4 s_box[NCLS][LBIN];
  __shared__ u32 s_cnt[NCLS];
  __shared__ u32 s_base[NCLS];
  __shared__ u32 s_cl[NCLS];
  int tid = threadIdx.x;
  int b = blockIdx.x / CHUNKS;
  int chunk = blockIdx.x % CHUNKS;
  int wave = tid >> 6, lane = tid & 63;
  if (tid < NCLS) s_cnt[tid] = 0u;
  __syncthreads();

  float H = (float)dh[0], W = (float)dw[0];
  const float4* props4 = (const float4*)props;
  const float4* breg4 = (const float4*)boxreg;

  for (int rloc = wave; rloc < RPB; rloc += 16) {
    int rl = chunk * RPB + rloc;
    if (rl >= NPER) break;
    int r = b * NPER + rl;
    const float* lrow = logits + (size_t)r * NC;
    float xA = lrow[lane];
    float xB = (lane < NC - 64) ? lrow[64 + lane] : -3.0e38f;
    float mx = fmaxf(xA, xB);
    for (int o = 32; o; o >>= 1) mx = fmaxf(mx, __shfl_xor(mx, o));
    float eA = expf(xA - mx);
    float eB = (lane < NC - 64) ? expf(xB - mx) : 0.0f;
    float sm = eA + eB;
    for (int o = 32; o; o >>= 1) sm += __shfl_xor(sm, o);
    float sA = eA / sm;
    float sB = eB / sm;
    bool eA_ok = (lane >= 1) && (sA > 0.05f);
    bool eB_ok = (lane < NC - 64) && (sB > 0.05f);
    if (eA_ok || eB_ok) {
      float4 p = props4[r];
      float w = p.z - p.x, h = p.w - p.y;
      float cx = p.x + 0.5f * w, cy = p.y + 0.5f * h;
      if (eA_ok) {
        float4 raw = decode_clip(breg4[(size_t)r * NC + lane], w, h, cx, cy, W, H);
        if (((raw.z - raw.x) >= 0.01f) && ((raw.w - raw.y) >= 0.01f)) {
          int ci = lane - 1;
          u32 orig = (u32)(rl * NCLS + ci);
          u64 key = ((u64)__float_as_uint(sA) << 22) | (u64)(0x3FFFFFu - orig);
          u32 lp = atomicAdd(&s_cnt[ci], 1u);
          if (lp < LBIN) { s_key[ci][lp] = key; s_box[ci][lp] = raw; }
          else {  // rare overflow: direct global (slot disjoint via same counter)
            u32 gp = atomicAdd(&bin_cnt[(b * NCLS + ci) * CSTRIDE], 1u);
            if (gp < BINCAP) {
              size_t o = ((size_t)b * NCLS + ci) * BINCAP + gp;
              bins_key[o] = key; bins_box[o] = raw;
            }
          }
        }
      }
      if (eB_ok) {
        float4 raw = decode_clip(breg4[(size_t)r * NC + 64 + lane], w, h, cx, cy, W, H);
        if (((raw.z - raw.x) >= 0.01f) && ((raw.w - raw.y) >= 0.01f)) {
          int ci = 63 + lane;
          u32 orig = (u32)(rl * NCLS + ci);
          u64 key = ((u64)__float_as_uint(sB) << 22) | (u64)(0x3FFFFFu - orig);
          u32 lp = atomicAdd(&s_cnt[ci], 1u);
          if (lp < LBIN) { s_key[ci][lp] = key; s_box[ci][lp] = raw; }
          else {
            u32 gp = atomicAdd(&bin_cnt[(b * NCLS + ci) * CSTRIDE], 1u);
            if (gp < BINCAP) {
              size_t o = ((size_t)b * NCLS + ci) * BINCAP + gp;
              bins_key[o] = key; bins_box[o] = raw;
            }
          }
        }
      }
    }
  }
  __syncthreads();
  if (tid < NCLS) {
    u32 cl = s_cnt[tid];
    if (cl > LBIN) cl = LBIN;
    s_cl[tid] = cl;
    s_base[tid] = cl ? atomicAdd(&bin_cnt[(b * NCLS + tid) * CSTRIDE], cl) : 0u;
  }
  __syncthreads();
  for (int idx = tid; idx < NCLS * LBIN; idx += 1024) {  // cooperative flush
    int ci = idx / LBIN, j = idx % LBIN;
    if ((u32)j < s_cl[ci]) {
      u32 p = s_base[ci] + (u32)j;
      if (p < BINCAP) {
        size_t o = ((size_t)b * NCLS + ci) * BINCAP + p;
        bins_key[o] = s_key[ci][j];
        bins_box[o] = s_box[ci][j];
      }
    }
  }
}

// Per-(image,class) greedy NMS. Rank sort (exact: keys unique) with LDS
// broadcast reads, conflict-free, no barriers in the rank loop; keys AND
// boxes scattered into sorted arrays. Waves 1-3 retire; wave 0 runs the
// ballot-greedy barrier-free.
__global__ __launch_bounds__(256) void k_nms_class(const u32* __restrict__ bin_cnt,
    const u64* __restrict__ bins_key, const float4* __restrict__ bins_box,
    u32* surv_cnt, u64* skey, float4* sbox,
    const int* __restrict__ dh, const int* __restrict__ dw) {
  __shared__ u64 k[BINCAP];       // unsorted keys
  __shared__ u64 ks[BINCAP];      // rank-sorted keys (desc)
  __shared__ float4 boxs[BINCAP]; // rank-sorted raw boxes
  __shared__ float4 s_sb[NDET];   // survivor offset boxes (IoU space)
  __shared__ float s_sa[NDET];
  __shared__ u64 s_sk[NDET];
  __shared__ u32 s_sid[NDET];     // survivor sorted-index

  int b = blockIdx.x / NCLS;
  int ci = blockIdx.x % NCLS;
  u32 cnt = bin_cnt[(b * NCLS + ci) * CSTRIDE];
  int n = (int)((cnt < BINCAP) ? cnt : BINCAP);
  if (n <= 0) return;

  int tid = threadIdx.x;
  float H = (float)dh[0], W = (float)dw[0];
  float loff = (fmaxf(H, W) + 1.0f) * (float)(ci + 1);
  size_t binb = ((size_t)b * NCLS + ci) * BINCAP;

  for (int j = tid; j < n; j += 256) k[j] = bins_key[binb + j];
  __syncthreads();
  for (int i = tid; i < n; i += 256) {
    u64 ki = k[i];
    u32 rank = 0;
    int j = 0;
    for (; j + 4 <= n; j += 4) {   // LDS broadcast reads, pipelined
      rank += (k[j] > ki) ? 1u : 0u;
      rank += (k[j + 1] > ki) ? 1u : 0u;
      rank += (k[j + 2] > ki) ? 1u : 0u;
      rank += (k[j + 3] > ki) ? 1u : 0u;
    }
    for (; j < n; ++j) rank += (k[j] > ki) ? 1u : 0u;
    ks[rank] = ki;
    boxs[rank] = bins_box[binb + i];
  }
  __syncthreads();
  if (tid >= 64) return;  // waves 1-3 done; wave 0 continues barrier-free

  int lane = tid;
  int S = 0;
  for (int base = 0; base < n && S < NDET; base += 64) {
    int i = base + lane;
    bool have = (i < n);
    u64 mykey = 0ull;
    float4 Bb = make_float4(0.f, 0.f, 0.f, 0.f);
    float aB = 0.f;
    if (have) {
      mykey = ks[i];
      float4 raw = boxs[i];
      Bb = make_float4(raw.x + loff, raw.y + loff, raw.z + loff, raw.w + loff);
      aB = (Bb.z - Bb.x) * (Bb.w - Bb.y);
    }
    bool alive = have;
    for (int s = 0; s < S; ++s) {   // suppression by earlier-chunk survivors
      float4 A = s_sb[s];
      float aA = s_sa[s];
      float ix1 = fmaxf(A.x, Bb.x), iy1 = fmaxf(A.y, Bb.y);
      float ix2 = fminf(A.z, Bb.z), iy2 = fminf(A.w, Bb.w);
      float inter = fmaxf(ix2 - ix1, 0.0f) * fmaxf(iy2 - iy1, 0.0f);
      float iou = inter / fmaxf(aA + aB - inter, 1e-9f);
      if (alive && iou > 0.5f) alive = false;
    }
    u64 mask = __ballot(alive);
    while (mask && S < NDET) {
      int j = __builtin_ctzll(mask);
      float Ax = __shfl(Bb.x, j), Ay = __shfl(Bb.y, j);
      float Az = __shfl(Bb.z, j), Aw = __shfl(Bb.w, j);
      float aA = __shfl(aB, j);
      if (lane == j) {
        s_sb[S] = Bb; s_sa[S] = aB; s_sk[S] = mykey; s_sid[S] = (u32)i;
      }
      float ix1 = fmaxf(Ax, Bb.x), iy1 = fmaxf(Ay, Bb.y);
      float ix2 = fminf(Az, Bb.z), iy2 = fminf(Aw, Bb.w);
      float inter = fmaxf(ix2 - ix1, 0.0f) * fmaxf(iy2 - iy1, 0.0f);
      float iou = inter / fmaxf(aA + aB - inter, 1e-9f);
      if (alive && iou > 0.5f) alive = false;  // selected lane leaves via IoU=1
      ++S;
      mask = __ballot(alive);
    }
  }
  if (S == 0) return;
  int basep = 0;
  if (lane == 0) basep = (int)atomicAdd(surv_cnt + b, (u32)S);
  basep = __shfl(basep, 0);
  for (int i2 = lane; i2 < S; i2 += 64) {
    u32 p = (u32)(basep + i2);
    if (p < SURVCAP) {
      skey[(size_t)b * SURVCAP + p] = s_sk[i2];
      sbox[(size_t)b * SURVCAP + p] = boxs[s_sid[i2]];
    }
  }
}

// Per-image exact top-NDET. 256 threads (4-wave barriers, 5x cheaper than
// R7-R8's 16-wave version whose 32x2 barriers cost ~20us). Scores in
// registers (VPT=36); bisection narrowed to the provable score interval
// (0.05, 1] -> 26 steps. Compacted pool (~110 entries) is RANK-SORTED by
// wave 0 (broadcast LDS reads, barrier-free, exact: 54-bit keys unique)
// straight into the 100 output slots -- no bitonic.
__global__ __launch_bounds__(256) void k_top(const u32* __restrict__ surv_cnt,
    const u64* __restrict__ skey, const float4* __restrict__ sbox, float* out) {
  __shared__ u32 ssc[SURVCAP];
  __shared__ u32 s_red[4];
  __shared__ u32 s_cnt[2];
  __shared__ u64 fk[FKCAP];
  __shared__ u32 fs[FKCAP];
  __shared__ u64 okey[NDET];
  __shared__ u32 osrc[NDET];

  int b = blockIdx.x;
  int tid = threadIdx.x;
  u32 ns = surv_cnt[b];
  if (ns > SURVCAP) ns = SURVCAP;
  const u64* kb = skey + (size_t)b * SURVCAP;

  u32 sc[VPT];
#pragma unroll
  for (int v = 0; v < VPT; ++v) {
    u32 j = (u32)tid + (u32)v * 256u;
    u32 s = 0u;
    if (j < ns) s = (u32)(kb[j] >> 22);
    sc[v] = s;
    ssc[j] = s;
  }
  if (tid == 0) { s_cnt[0] = 0; s_cnt[1] = 0; }
  __syncthreads();

  u32 T = 0;
  if (ns > NDET) {
    // minimal x with count(s>x) < NDET == 100th-largest score value.
    // All scores s satisfy 0.05f < s <= 1.0f (softmax w/ RN monotonicity),
    // i.e. bits in [0x3D4CCCCE, 0x3F800000]: condition false below lo,
    // true at hi.
    u32 lo = 0x3D4CCCCEu, hi = 0x3F800001u;
    while (lo < hi) {
      u32 mid = lo + ((hi - lo) >> 1);
      u32 c = 0;
#pragma unroll
      for (int v = 0; v < VPT; ++v) c += (sc[v] > mid) ? 1u : 0u;
      for (int o = 32; o; o >>= 1) c += __shfl_xor(c, o);
      if ((tid & 63) == 0) s_red[tid >> 6] = c;
      __syncthreads();
      u32 totc = s_red[0] + s_red[1] + s_red[2] + s_red[3];
      __syncthreads();
      if (totc < NDET) hi = mid; else lo = mid + 1;
    }
    T = lo;
  }
  __syncthreads();

  for (u32 j = tid; j < ns; j += 256) {
    bool take = (ns <= NDET) || (ssc[j] > T);
    if (take) {
      u32 p = atomicAdd(&s_cnt[0], 1u);
      if (p < FKCAP) { fk[p] = kb[j]; fs[p] = j; }
    }
  }
  __syncthreads();
  if (tid == 0) s_cnt[1] = s_cnt[0];
  __syncthreads();
  if (ns > NDET) {  // append ==T ties; order fixed by the rank sort below
    for (u32 j = tid; j < ns; j += 256) {
      if (ssc[j] == T) {
        u32 p = atomicAdd(&s_cnt[1], 1u);
        if (p < FKCAP) { fk[p] = kb[j]; fs[p] = j; }
      }
    }
  }
  __syncthreads();
  u32 tot = s_cnt[1];
  if (tot > FKCAP) tot = FKCAP;
  if (tid >= 64) return;  // wave 0 finishes barrier-free

  for (int i = tid; i < NDET; i += 64) okey[i] = 0ull;
  for (int i = tid; i < (int)tot; i += 64) {
    u64 ki = fk[i];
    u32 rank = 0;
    for (int j = 0; j < (int)tot; ++j) rank += (fk[j] > ki) ? 1u : 0u;
    if (rank < NDET) { okey[rank] = ki; osrc[rank] = fs[i]; }
  }
  // boxes[3200] | scores[800] | labels[800] | keep[800]
  for (int i = tid; i < NDET; i += 64) {
    u64 key = okey[i];
    float b0 = 0.f, b1 = 0.f, b2 = 0.f, b3 = 0.f, sc2 = 0.f, lb = 0.f, kp = 0.f;
    if (key) {
      float4 bx = sbox[(size_t)b * SURVCAP + osrc[i]];
      b0 = bx.x; b1 = bx.y; b2 = bx.z; b3 = bx.w;
      sc2 = __uint_as_float((u32)(key >> 22));
      u32 orig = 0x3FFFFFu - (u32)(key & 0x3FFFFFu);
      lb = (float)(orig % NCLS + 1u);
      kp = 1.0f;
    }
    float* ob = out + ((size_t)b * NDET + i) * 4;
    ob[0] = b0; ob[1] = b1; ob[2] = b2; ob[3] = b3;
    out[NB * NDET * 4 + b * NDET + i] = sc2;
    out[NB * NDET * 5 + b * NDET + i] = lb;
    out[NB * NDET * 6 + b * NDET + i] = kp;
  }
}

// ---------------------------------------------------------------- launch ----
extern "C" void kernel_launch(void* const* d_in, const int* in_sizes, int n_in,
                              void* d_out, int out_size, void* d_ws, size_t ws_size,
                              hipStream_t stream) {
  const float* logits = (const float*)d_in[0];
  const float* boxreg = (const float*)d_in[1];
  const float* props  = (const float*)d_in[2];
  const int* dh = (const int*)d_in[3];
  const int* dw = (const int*)d_in[4];
  float* out = (float*)d_out;

  char* ws = (char*)d_ws;
  u32* bin_cnt  = (u32*)ws;                                   // 720*16 u32 = 45 KiB
  u32* surv_cnt = (u32*)(ws + 46080);                         // 8 u32
  u64* bins_key = (u64*)(ws + 46336);                         // 720*512*8  = 2.95 MB
  char* p1 = ws + 46336 + (size_t)NB * NCLS * BINCAP * 8;
  float4* bins_box = (float4*)p1;                             // 720*512*16 = 5.9 MB
  char* p2 = p1 + (size_t)NB * NCLS * BINCAP * 16;
  u64* skey = (u64*)p2;                                       // 8*9216*8 = 590 KB
  float4* sbox = (float4*)(p2 + (size_t)NB * SURVCAP * 8);    // 8*9216*16 = 1.18 MB
  (void)ws_size;

  k_zero<<<1, 1024, 0, stream>>>(bin_cnt, surv_cnt);
  k_score<<<NB * CHUNKS, 1024, 0, stream>>>(logits, boxreg, props, dh, dw,
                                            bin_cnt, bins_key, bins_box);
  k_nms_class<<<NB * NCLS, 256, 0, stream>>>(bin_cnt, bins_key, bins_box,
                                             surv_cnt, skey, sbox, dh, dw);
  k_top<<<NB, 256, 0, stream>>>(surv_cnt, skey, sbox, out);
}

// Round 10
// 174.159 us; speedup vs baseline: 1.2474x; 1.0813x over previous
//
#include <hip/hip_runtime.h>
#include <stdint.h>

typedef uint32_t u32;
typedef unsigned long long u64;

#define NB 8
#define NPER 4000
#define NC 91
#define NCLS 90
#define NDET 100
#define CHUNKS 64
#define RPB 63         // rows per k_score block; 64*63=4032 covers 4000 w/ guard
#define LBIN 16        // LDS staging per class per chunk (avg ~1.6 used)
#define CCAP 63        // per-(chunk,class) global bin cap == rows/chunk (EXACT:
                       // each (row,class) yields at most one candidate)
#define BINCAP 512     // per-(image,class) NMS pool clamp (avg ~103)
#define SURVCAP 9216   // fixed survivor slots: 90 classes x 100 + pad
#define NSFIX (NCLS * NDET)  // 9000 real slots
#define FKCAP 1024     // k_top compacted pool (100 + score ties)
#define VPT 36         // k_top values/thread = SURVCAP/256

// ---------------------------------------------------------------- decode ----
// bit-identical to reference op order (verified absmax 0.0 in R1-R9)
__device__ __forceinline__ float4 decode_clip(float4 rel, float w, float h,
                                              float cx, float cy, float W, float H) {
  const float XCLIP = 4.135166556742356f;  // log(1000/16)
  float dx = rel.x / 10.0f;
  float dy = rel.y / 10.0f;
  float dw = fminf(rel.z / 5.0f, XCLIP);
  float dh = fminf(rel.w / 5.0f, XCLIP);
  float qcx = dx * w + cx;
  float qcy = dy * h + cy;
  float qw = expf(dw) * w;
  float qh = expf(dh) * h;
  float x1 = qcx - 0.5f * qw, y1 = qcy - 0.5f * qh;
  float x2 = qcx + 0.5f * qw, y2 = qcy + 0.5f * qh;
  x1 = fminf(fmaxf(x1, 0.0f), W);
  x2 = fminf(fmaxf(x2, 0.0f), W);
  y1 = fminf(fmaxf(y1, 0.0f), H);
  y2 = fminf(fmaxf(y2, 0.0f), H);
  return make_float4(x1, y1, x2, y2);
}

__device__ __forceinline__ float rdlane(float v, int sl) {
  return __int_as_float(__builtin_amdgcn_readlane(__float_as_int(v), sl));
}

// ---------------------------------------------------------------- kernels ---
// Front-end: softmax + decode + filter, writing to BLOCK-PRIVATE per-chunk
// class bins (no global atomics, no pre-zeroed counters -> no k_zero).
// LDS stages the first LBIN per class; slots LBIN..CCAP-1 store directly to
// this block's private global region (slot index from the LDS count).
__global__ __launch_bounds__(1024) void k_score(const float* __restrict__ logits,
    const float* __restrict__ boxreg, const float* __restrict__ props,
    const int* __restrict__ dh, const int* __restrict__ dw,
    u32* cnt_g, u64* bins_key, float4* bins_box) {
  __shared__ u64 s_key[NCLS][LBIN];
  __shared__ float4 s_box[NCLS][LBIN];
  __shared__ u32 s_cnt[NCLS];
  int tid = threadIdx.x;
  int b = blockIdx.x / CHUNKS;
  int chunk = blockIdx.x % CHUNKS;
  int wave = tid >> 6, lane = tid & 63;
  if (tid < NCLS) s_cnt[tid] = 0u;
  __syncthreads();

  float H = (float)dh[0], W = (float)dw[0];
  const float4* props4 = (const float4*)props;
  const float4* breg4 = (const float4*)boxreg;
  size_t chbase = ((size_t)(b * CHUNKS + chunk)) * NCLS;  // *CCAP for bins

  for (int rloc = wave; rloc < RPB; rloc += 16) {
    int rl = chunk * RPB + rloc;
    if (rl >= NPER) break;
    int r = b * NPER + rl;
    const float* lrow = logits + (size_t)r * NC;
    float xA = lrow[lane];
    float xB = (lane < NC - 64) ? lrow[64 + lane] : -3.0e38f;
    float mx = fmaxf(xA, xB);
    for (int o = 32; o; o >>= 1) mx = fmaxf(mx, __shfl_xor(mx, o));
    float eA = expf(xA - mx);
    float eB = (lane < NC - 64) ? expf(xB - mx) : 0.0f;
    float sm = eA + eB;
    for (int o = 32; o; o >>= 1) sm += __shfl_xor(sm, o);
    float sA = eA / sm;
    float sB = eB / sm;
    bool eA_ok = (lane >= 1) && (sA > 0.05f);
    bool eB_ok = (lane < NC - 64) && (sB > 0.05f);
    if (eA_ok || eB_ok) {
      float4 p = props4[r];
      float w = p.z - p.x, h = p.w - p.y;
      float cx = p.x + 0.5f * w, cy = p.y + 0.5f * h;
      if (eA_ok) {
        float4 raw = decode_clip(breg4[(size_t)r * NC + lane], w, h, cx, cy, W, H);
        if (((raw.z - raw.x) >= 0.01f) && ((raw.w - raw.y) >= 0.01f)) {
          int ci = lane - 1;
          u32 orig = (u32)(rl * NCLS + ci);
          u64 key = ((u64)__float_as_uint(sA) << 22) | (u64)(0x3FFFFFu - orig);
          u32 lp = atomicAdd(&s_cnt[ci], 1u);  // LDS only
          if (lp < LBIN) { s_key[ci][lp] = key; s_box[ci][lp] = raw; }
          else if (lp < CCAP) {  // private global slot, no atomic
            size_t o = (chbase + ci) * CCAP + lp;
            bins_key[o] = key; bins_box[o] = raw;
          }
        }
      }
      if (eB_ok) {
        float4 raw = decode_clip(breg4[(size_t)r * NC + 64 + lane], w, h, cx, cy, W, H);
        if (((raw.z - raw.x) >= 0.01f) && ((raw.w - raw.y) >= 0.01f)) {
          int ci = 63 + lane;
          u32 orig = (u32)(rl * NCLS + ci);
          u64 key = ((u64)__float_as_uint(sB) << 22) | (u64)(0x3FFFFFu - orig);
          u32 lp = atomicAdd(&s_cnt[ci], 1u);
          if (lp < LBIN) { s_key[ci][lp] = key; s_box[ci][lp] = raw; }
          else if (lp < CCAP) {
            size_t o = (chbase + ci) * CCAP + lp;
            bins_key[o] = key; bins_box[o] = raw;
          }
        }
      }
    }
  }
  __syncthreads();
  if (tid < NCLS) cnt_g[chbase + tid] = s_cnt[tid];  // plain store, no zeroing needed
  for (int idx = tid; idx < NCLS * LBIN; idx += 1024) {  // cooperative LDS flush
    int ci = idx / LBIN, j = idx % LBIN;
    if ((u32)j < s_cnt[ci]) {
      size_t o = (chbase + ci) * CCAP + (u32)j;
      bins_key[o] = s_key[ci][j];
      bins_box[o] = s_box[ci][j];
    }
  }
}

// Per-(image,class) greedy NMS. Gather: wave 0, lane==chunk, wave-scan for
// offsets (no atomics). Rank sort (keys unique -> exact permutation) by all
// 256 threads via LDS broadcast reads. Greedy: wave 0, barrier-free; the
// serial per-survivor broadcast uses v_readlane (uniform index from
// ctz(ballot)) instead of 5 dependent DS-routed shfls (R9's ~40us chain).
// Survivors land in FIXED slots skey[b][ci*100..], zero-padded (no atomic).
__global__ __launch_bounds__(256) void k_nms_class(const u32* __restrict__ cnt_g,
    const u64* __restrict__ bins_key, const float4* __restrict__ bins_box,
    u64* skey, float4* sbox, const int* __restrict__ dh, const int* __restrict__ dw) {
  __shared__ u64 k[BINCAP];       // unsorted keys
  __shared__ float4 boxu[BINCAP]; // unsorted boxes
  __shared__ u64 ks[BINCAP];      // rank-sorted keys (desc)
  __shared__ float4 boxs[BINCAP]; // rank-sorted boxes
  __shared__ float4 s_sb[NDET];   // survivor offset boxes (IoU space)
  __shared__ float s_sa[NDET];
  __shared__ u64 s_sk[NDET];
  __shared__ u32 s_sid[NDET];
  __shared__ u32 s_n;

  int b = blockIdx.x / NCLS;
  int ci = blockIdx.x % NCLS;
  int tid = threadIdx.x;
  u64* outk = skey + (size_t)b * SURVCAP + (size_t)ci * NDET;
  float4* outb = sbox + (size_t)b * SURVCAP + (size_t)ci * NDET;

  if (tid < 64) {  // lane == chunk
    u32 cntc = cnt_g[((size_t)(b * CHUNKS + tid)) * NCLS + ci];
    if (cntc > CCAP) cntc = CCAP;
    u32 inc = cntc;
    for (int o = 1; o < 64; o <<= 1) {
      u32 v = __shfl_up(inc, o);
      if (tid >= o) inc += v;
    }
    u32 off = inc - cntc;
    if (tid == 63) s_n = inc;
    size_t src = (((size_t)(b * CHUNKS + tid)) * NCLS + ci) * CCAP;
    for (u32 i = 0; i < cntc; ++i) {
      u32 d = off + i;
      if (d < BINCAP) { k[d] = bins_key[src + i]; boxu[d] = bins_box[src + i]; }
    }
  }
  __syncthreads();
  int n = (int)s_n;
  if (n > BINCAP) n = BINCAP;
  if (n <= 0) {
    for (int i = tid; i < NDET; i += 256) outk[i] = 0ull;
    return;
  }
  for (int i = tid; i < n; i += 256) {  // rank sort: broadcast reads, no barriers
    u64 ki = k[i];
    u32 rank = 0;
    int j = 0;
    for (; j + 4 <= n; j += 4) {
      rank += (k[j] > ki) ? 1u : 0u;
      rank += (k[j + 1] > ki) ? 1u : 0u;
      rank += (k[j + 2] > ki) ? 1u : 0u;
      rank += (k[j + 3] > ki) ? 1u : 0u;
    }
    for (; j < n; ++j) rank += (k[j] > ki) ? 1u : 0u;
    ks[rank] = ki;
    boxs[rank] = boxu[i];
  }
  __syncthreads();
  if (tid >= 64) return;  // wave 0 continues barrier-free

  float H = (float)dh[0], W = (float)dw[0];
  float loff = (fmaxf(H, W) + 1.0f) * (float)(ci + 1);
  int lane = tid;
  int S = 0;
  for (int base = 0; base < n && S < NDET; base += 64) {
    int i = base + lane;
    bool have = (i < n);
    u64 mykey = 0ull;
    float4 Bb = make_float4(0.f, 0.f, 0.f, 0.f);
    float aB = 0.f;
    if (have) {
      mykey = ks[i];
      float4 raw = boxs[i];
      Bb = make_float4(raw.x + loff, raw.y + loff, raw.z + loff, raw.w + loff);
      aB = (Bb.z - Bb.x) * (Bb.w - Bb.y);
    }
    bool alive = have;
    for (int s = 0; s < S; ++s) {  // independent LDS reads, pipelined
      float4 A = s_sb[s];
      float aA = s_sa[s];
      float ix1 = fmaxf(A.x, Bb.x), iy1 = fmaxf(A.y, Bb.y);
      float ix2 = fminf(A.z, Bb.z), iy2 = fminf(A.w, Bb.w);
      float inter = fmaxf(ix2 - ix1, 0.0f) * fmaxf(iy2 - iy1, 0.0f);
      float iou = inter / fmaxf(aA + aB - inter, 1e-9f);
      if (alive && iou > 0.5f) alive = false;
    }
    u64 mask = __ballot(alive);
    while (mask && S < NDET) {
      int j = __builtin_ctzll(mask);                    // wave-uniform
      int js = __builtin_amdgcn_readfirstlane(j);       // pin scalar
      float Ax = rdlane(Bb.x, js), Ay = rdlane(Bb.y, js);
      float Az = rdlane(Bb.z, js), Aw = rdlane(Bb.w, js);
      float aA = rdlane(aB, js);
      if (lane == js) {
        s_sb[S] = Bb; s_sa[S] = aB; s_sk[S] = mykey; s_sid[S] = (u32)i;
      }
      float ix1 = fmaxf(Ax, Bb.x), iy1 = fmaxf(Ay, Bb.y);
      float ix2 = fminf(Az, Bb.z), iy2 = fminf(Aw, Bb.w);
      float inter = fmaxf(ix2 - ix1, 0.0f) * fmaxf(iy2 - iy1, 0.0f);
      float iou = inter / fmaxf(aA + aB - inter, 1e-9f);
      if (alive && iou > 0.5f) alive = false;  // selected lane leaves via IoU=1
      ++S;
      mask = __ballot(alive);
    }
  }
  for (int i2 = lane; i2 < NDET; i2 += 64) {  // fixed slots, zero-padded
    if (i2 < S) {
      outk[i2] = s_sk[i2];
      outb[i2] = boxs[s_sid[i2]];
    } else {
      outk[i2] = 0ull;
    }
  }
}

// Per-image exact top-NDET over the fixed 9000 survivor slots (key==0 =
// empty, never selectable: T >= 0.05f bits > 0). Register-resident
// bisection on [0.05f, 1.0f] bits for the 100th-largest score T; compact
// >T plus ==T ties; wave-0 rank sort (keys unique) into the 100 outputs.
__global__ __launch_bounds__(256) void k_top(const u64* __restrict__ skey,
    const float4* __restrict__ sbox, float* out) {
  __shared__ u32 ssc[SURVCAP];
  __shared__ u32 s_red[4];
  __shared__ u32 s_cnt[2];
  __shared__ u64 fk[FKCAP];
  __shared__ u32 fs[FKCAP];
  __shared__ u64 okey[NDET];
  __shared__ u32 osrc[NDET];

  int b = blockIdx.x;
  int tid = threadIdx.x;
  const u64* kb = skey + (size_t)b * SURVCAP;

  u32 sc[VPT];
#pragma unroll
  for (int v = 0; v < VPT; ++v) {
    u32 j = (u32)tid + (u32)v * 256u;
    u32 s = 0u;
    if (j < NSFIX) s = (u32)(kb[j] >> 22);
    sc[v] = s;
    ssc[j] = s;
  }
  if (tid == 0) { s_cnt[0] = 0; s_cnt[1] = 0; }
  __syncthreads();

  // minimal x with count(s > x) < NDET; scores in (0.05, 1] => bits in
  // [0x3D4CCCCE, 0x3F800000]. If fewer than NDET survivors exist total,
  // bisection converges to lo and the ==T append collects the boundary.
  u32 lo = 0x3D4CCCCEu, hi = 0x3F800001u;
  while (lo < hi) {
    u32 mid = lo + ((hi - lo) >> 1);
    u32 c = 0;
#pragma unroll
    for (int v = 0; v < VPT; ++v) c += (sc[v] > mid) ? 1u : 0u;
    for (int o = 32; o; o >>= 1) c += __shfl_xor(c, o);
    if ((tid & 63) == 0) s_red[tid >> 6] = c;
    __syncthreads();
    u32 totc = s_red[0] + s_red[1] + s_red[2] + s_red[3];
    __syncthreads();
    if (totc < NDET) hi = mid; else lo = mid + 1;
  }
  u32 T = lo;
  __syncthreads();

  for (u32 j = tid; j < NSFIX; j += 256) {
    if (ssc[j] > T) {
      u32 p = atomicAdd(&s_cnt[0], 1u);
      if (p < FKCAP) { fk[p] = kb[j]; fs[p] = j; }
    }
  }
  __syncthreads();
  if (tid == 0) s_cnt[1] = s_cnt[0];
  __syncthreads();
  for (u32 j = tid; j < NSFIX; j += 256) {  // ==T ties; order fixed by rank sort
    if (ssc[j] == T) {
      u32 p = atomicAdd(&s_cnt[1], 1u);
      if (p < FKCAP) { fk[p] = kb[j]; fs[p] = j; }
    }
  }
  __syncthreads();
  u32 tot = s_cnt[1];
  if (tot > FKCAP) tot = FKCAP;
  if (tid >= 64) return;  // wave 0 finishes barrier-free

  for (int i = tid; i < NDET; i += 64) okey[i] = 0ull;
  for (int i = tid; i < (int)tot; i += 64) {
    u64 ki = fk[i];
    u32 rank = 0;
    for (int j = 0; j < (int)tot; ++j) rank += (fk[j] > ki) ? 1u : 0u;
    if (rank < NDET) { okey[rank] = ki; osrc[rank] = fs[i]; }
  }
  // boxes[3200] | scores[800] | labels[800] | keep[800]
  for (int i = tid; i < NDET; i += 64) {
    u64 key = okey[i];
    float b0 = 0.f, b1 = 0.f, b2 = 0.f, b3 = 0.f, sc2 = 0.f, lb = 0.f, kp = 0.f;
    if (key) {
      float4 bx = sbox[(size_t)b * SURVCAP + osrc[i]];
      b0 = bx.x; b1 = bx.y; b2 = bx.z; b3 = bx.w;
      sc2 = __uint_as_float((u32)(key >> 22));
      u32 orig = 0x3FFFFFu - (u32)(key & 0x3FFFFFu);
      lb = (float)(orig % NCLS + 1u);
      kp = 1.0f;
    }
    float* ob = out + ((size_t)b * NDET + i) * 4;
    ob[0] = b0; ob[1] = b1; ob[2] = b2; ob[3] = b3;
    out[NB * NDET * 4 + b * NDET + i] = sc2;
    out[NB * NDET * 5 + b * NDET + i] = lb;
    out[NB * NDET * 6 + b * NDET + i] = kp;
  }
}

// ---------------------------------------------------------------- launch ----
extern "C" void kernel_launch(void* const* d_in, const int* in_sizes, int n_in,
                              void* d_out, int out_size, void* d_ws, size_t ws_size,
                              hipStream_t stream) {
  const float* logits = (const float*)d_in[0];
  const float* boxreg = (const float*)d_in[1];
  const float* props  = (const float*)d_in[2];
  const int* dh = (const int*)d_in[3];
  const int* dw = (const int*)d_in[4];
  float* out = (float*)d_out;

  char* ws = (char*)d_ws;
  // cnt_g: 8*64*90 u32 = 180 KiB (written every call, no zeroing needed)
  u32* cnt_g = (u32*)ws;
  char* p0 = ws + ((size_t)NB * CHUNKS * NCLS * 4 + 255 & ~(size_t)255);
  u64* bins_key = (u64*)p0;                                   // 8*64*90*63*8  = 23.2 MB
  char* p1 = p0 + (size_t)NB * CHUNKS * NCLS * CCAP * 8;
  float4* bins_box = (float4*)p1;                             // 8*64*90*63*16 = 46.4 MB
  char* p2 = p1 + (size_t)NB * CHUNKS * NCLS * CCAP * 16;
  u64* skey = (u64*)p2;                                       // 8*9216*8 = 590 KB
  float4* sbox = (float4*)(p2 + (size_t)NB * SURVCAP * 8);    // 8*9216*16 = 1.18 MB
  (void)ws_size;

  k_score<<<NB * CHUNKS, 1024, 0, stream>>>(logits, boxreg, props, dh, dw,
                                            cnt_g, bins_key, bins_box);
  k_nms_class<<<NB * NCLS, 256, 0, stream>>>(cnt_g, bins_key, bins_box,
                                             skey, sbox, dh, dw);
  k_top<<<NB, 256, 0, stream>>>(skey, sbox, out);
}